// Round 6
// baseline (170.565 us; speedup 1.0000x reference)
//
#include <hip/hip_runtime.h>

// Skeleton FK, algebraically simplified (frame-change G cancels):
//   q[c] = q[parent] + R[b,parent] @ v[c],  v[c] = (off[c][1], off[c][2], off[c][0])
//   out[b,c,:] = q[c]
//
// Round-6: round-5's persistent counted-vmcnt pipeline with two fixes:
//  (1) offsets preloaded into SSA registers (immune to asm "memory"
//      clobbers -- R5 was re-loading off[] from global inside every tile);
//  (2) vmcnt accounting includes the 18 output stores; first iteration
//      peeled (no stores outstanding yet). No sched_barriers (all hazards
//      are memory<->memory, ordered by the clobber already).
//
// Steady-state outstanding at loop top (issue order, in-order retirement):
//   A_n(23), B_n(21), stores_{n-1}(18) = 62
//   WAITVM(39) -> retires exactly A_n.  After ISSUE_A(t+G): 62 again;
//   WAITVM(41) -> retires exactly B_n.  Iter0: 44/44 outstanding -> 21/23.

#define NJ    24
#define GRID  768            // 3 blocks/CU (LDS-bound) * 256 CU

typedef const __attribute__((address_space(1))) void* gptr_t;
typedef __attribute__((address_space(3))) void* lptr_t;

#define WAITVM(n) asm volatile("s_waitcnt vmcnt(" #n ")" ::: "memory")
#define WAITLG()  asm volatile("s_waitcnt lgkmcnt(0)" ::: "memory")

__global__ __launch_bounds__(64, 1) void fk_kernel(
    const float* __restrict__ ori,   // [B, 216]
    const float* __restrict__ off,   // [24, 3]
    float* __restrict__ out,         // [B, 72]
    int nt)                          // number of 64-row tiles (8192)
{
    const int l = threadIdx.x;                       // 0..63, one wave/block
    __shared__ alignas(16) float4 s4[64 * 44];       // 45056 B
    float4* const bufA = s4;                         // rows: stride 23 f4
    float4* const bufB = s4 + 64 * 23;               // rows: stride 21 f4

    // ---- Offsets into SSA registers (one-time global loads) ----
#define VO(c) const float vx##c = off[3*(c)+1], vy##c = off[3*(c)+2], \
                          vz##c = off[3*(c)+0];
    VO(1)  VO(2)  VO(3)  VO(4)  VO(5)  VO(6)  VO(7)  VO(8)
    VO(9)  VO(10) VO(11) VO(12) VO(13) VO(14) VO(15) VO(16)
    VO(17) VO(18) VO(19) VO(20) VO(21) VO(22) VO(23)
#undef VO

    // Per-lane gather offsets (floats), tile-invariant, SSA.
    unsigned offA[23], offB[21];
#pragma unroll
    for (int i = 0; i < 23; ++i) {
        unsigned idx = (unsigned)(i * 64 + l), row = idx / 23u, w = idx - row * 23u;
        offA[i] = row * 216u + w * 4u;
    }
#pragma unroll
    for (int i = 0; i < 21; ++i) {
        unsigned idx = (unsigned)(i * 64 + l), row = idx / 21u, w = idx - row * 21u;
        unsigned g = (w < 7u) ? (w + 27u) : (w + 29u);
        offB[i] = row * 216u + g * 4u;
    }

#define ISSUE_A(t) do { const float* gb = ori + (size_t)(t) * (64 * 216); \
    _Pragma("unroll") for (int i = 0; i < 23; ++i) \
        __builtin_amdgcn_global_load_lds((gptr_t)(gb + offA[i]), \
                                         (lptr_t)(&bufA[i * 64]), 16, 0, 0); } while (0)
#define ISSUE_B(t) do { const float* gb = ori + (size_t)(t) * (64 * 216); \
    _Pragma("unroll") for (int i = 0; i < 21; ++i) \
        __builtin_amdgcn_global_load_lds((gptr_t)(gb + offB[i]), \
                                         (lptr_t)(&bufB[i * 64]), 16, 0, 0); } while (0)

    float qx[NJ], qy[NJ], qz[NJ];
    qx[0] = 0.0f; qy[0] = 0.0f; qz[0] = 0.0f;

#define LOADM(rb, o) { \
    const float4 w0 = (rb)[(o)/4 + 0]; \
    const float4 w1 = (rb)[(o)/4 + 1]; \
    const float4 w2 = (rb)[(o)/4 + 2]; \
    const float tt[12] = {w0.x,w0.y,w0.z,w0.w, w1.x,w1.y,w1.z,w1.w, \
                          w2.x,w2.y,w2.z,w2.w}; \
    r[0]=tt[(o)%4+0]; r[1]=tt[(o)%4+1]; r[2]=tt[(o)%4+2]; \
    r[3]=tt[(o)%4+3]; r[4]=tt[(o)%4+4]; r[5]=tt[(o)%4+5]; \
    r[6]=tt[(o)%4+6]; r[7]=tt[(o)%4+7]; r[8]=tt[(o)%4+8]; }

#define CHILD(p, c) { \
    qx[c] = fmaf(r[0], vx##c, fmaf(r[1], vy##c, fmaf(r[2], vz##c, qx[p]))); \
    qy[c] = fmaf(r[3], vx##c, fmaf(r[4], vy##c, fmaf(r[5], vz##c, qy[p]))); \
    qz[c] = fmaf(r[6], vx##c, fmaf(r[7], vy##c, fmaf(r[8], vz##c, qz[p]))); }

#define COMPUTE_A() do { const float4* rb = &bufA[l * 23]; float r[9]; \
    LOADM(rb, 0);   CHILD(0, 1);  CHILD(0, 2);  CHILD(0, 3); \
    LOADM(rb, 9);   CHILD(1, 4); \
    LOADM(rb, 18);  CHILD(2, 5); \
    LOADM(rb, 27);  CHILD(3, 6); \
    LOADM(rb, 36);  CHILD(4, 7); \
    LOADM(rb, 45);  CHILD(5, 8); \
    LOADM(rb, 54);  CHILD(6, 9); \
    LOADM(rb, 63);  CHILD(7, 10); \
    LOADM(rb, 72);  CHILD(8, 11); \
    LOADM(rb, 81);  CHILD(9, 12); CHILD(9, 13); CHILD(9, 14); } while (0)

#define COMPUTE_B() do { const float4* rb = &bufB[l * 21]; float r[9]; \
    LOADM(rb, 0);   CHILD(12, 15); \
    LOADM(rb, 9);   CHILD(13, 16); \
    LOADM(rb, 18);  CHILD(14, 17); \
    LOADM(rb, 28);  CHILD(16, 18); \
    LOADM(rb, 37);  CHILD(17, 19); \
    LOADM(rb, 46);  CHILD(18, 20); \
    LOADM(rb, 55);  CHILD(19, 21); \
    LOADM(rb, 64);  CHILD(20, 22); \
    LOADM(rb, 73);  CHILD(21, 23); } while (0)

    // ---- Persistent tile loop with cross-tile counted-vmcnt pipeline ----
    unsigned t = blockIdx.x;
    ISSUE_A(t);
    ISSUE_B(t);
    bool first = true;

    for (;;) {
        const bool more = (t + GRID < (unsigned)nt);

        if (first) { WAITVM(21); } else { WAITVM(39); }   // A(t) resident
        COMPUTE_A();
        WAITLG();                      // A-reads retired before overwrite DMA
        if (more) ISSUE_A(t + GRID);

        if (!more)      { WAITVM(0);  }
        else if (first) { WAITVM(23); }                   // B(t) resident
        else            { WAITVM(41); }
        COMPUTE_B();

        // Stage output in bufB (rows consumed), readback coalesced.
        float fv[72];
#pragma unroll
        for (int i = 0; i < NJ; ++i) {
            fv[3*i+0] = qx[i]; fv[3*i+1] = qy[i]; fv[3*i+2] = qz[i];
        }
#pragma unroll
        for (int j = 0; j < 18; ++j)
            bufB[l * 21 + j] = make_float4(fv[4*j+0], fv[4*j+1], fv[4*j+2], fv[4*j+3]);

        float4 ro[18];
#pragma unroll
        for (int j = 0; j < 18; ++j) {
            const unsigned g2 = (unsigned)(j * 64 + l);
            const unsigned r2 = g2 / 18u;
            const unsigned w2 = g2 - r2 * 18u;
            ro[j] = bufB[r2 * 21u + w2];
        }
        WAITLG();                      // readback in regs before overwrite DMA
        if (more) ISSUE_B(t + GRID);

        float4* __restrict__ o4 = (float4*)(out + (size_t)t * (64 * 72));
#pragma unroll
        for (int j = 0; j < 18; ++j)
            o4[j * 64 + l] = ro[j];

        if (!more) break;
        t += GRID;
        first = false;
    }

#undef ISSUE_A
#undef ISSUE_B
#undef LOADM
#undef CHILD
#undef COMPUTE_A
#undef COMPUTE_B
}

extern "C" void kernel_launch(void* const* d_in, const int* in_sizes, int n_in,
                              void* d_out, int out_size, void* d_ws, size_t ws_size,
                              hipStream_t stream) {
    const float* ori = (const float*)d_in[0];   // [B,24,3,3] fp32
    const float* off = (const float*)d_in[1];   // [24,3] fp32
    float* out = (float*)d_out;                 // [B,24,3] fp32

    int B  = in_sizes[0] / 216;                 // 524288
    int nt = B / 64;                            // 8192 tiles
    hipLaunchKernelGGL(fk_kernel, dim3(GRID), dim3(64), 0, stream,
                       ori, off, out, nt);
}

// Round 7
// 119.636 us; speedup vs baseline: 1.4257x; 1.4257x over previous
//
#include <hip/hip_runtime.h>

// Skeleton FK, algebraically simplified (frame-change G cancels):
//   q[c] = q[parent] + R[b,parent] @ v[c],  v[c] = (off[c][1], off[c][2], off[c][0])
//   out[b,c,:] = q[c]
//
// Round-7 = round-4 structure (one 64-row tile per 1-wave block, two-stage
// tree split) with ONE change: both stages' DMAs issue up front into
// separate LDS buffers, counted vmcnt(21) gates stage-A compute, vmcnt(0)
// gates stage-B. B's HBM latency hides under A's compute; one drain per
// tile instead of two. No persistence, no cross-tile state, no stores
// outstanding at any wait -> counted-vmcnt arithmetic is exact.
//   bufA: matrices 0..9   = row f4  0..22, stride 23 (odd -> conflict-free)
//   bufB: matrices 12..14 = f4 27..33, 16..21 = f4 36..49, compact stride 21
// Output staged in bufA (stride 19) then fully coalesced stores.

#define NJ 24

typedef const __attribute__((address_space(1))) void* gptr_t;
typedef __attribute__((address_space(3))) void* lptr_t;

#define WAITVM(n) asm volatile("s_waitcnt vmcnt(" #n ")" ::: "memory")

__global__ __launch_bounds__(64) void fk_kernel(
    const float* __restrict__ ori,   // [B, 216]
    const float* __restrict__ off,   // [24, 3]
    float* __restrict__ out,         // [B, 72]
    int nt)
{
    const int l = threadIdx.x;                       // 0..63, one wave/block
    const long long tile = blockIdx.x;
    const float* __restrict__ gbase = ori + tile * (64LL * 216);

    __shared__ alignas(16) float4 s4[64 * 44];       // 45056 B
    float4* const bufA = s4;                         // stride 23 f4
    float4* const bufB = s4 + 64 * 23;               // stride 21 f4

    // ---- Issue ALL 44 DMAs up front (A then B, in order) ----
#pragma unroll
    for (int i = 0; i < 23; ++i) {
        const unsigned idx = (unsigned)(i * 64 + l);
        const unsigned row = idx / 23u;
        const unsigned w   = idx - row * 23u;
        const float* src = gbase + (size_t)row * 216u + (size_t)w * 4u;
        __builtin_amdgcn_global_load_lds((gptr_t)src, (lptr_t)(&bufA[i * 64]),
                                         16, 0, 0);
    }
#pragma unroll
    for (int i = 0; i < 21; ++i) {
        const unsigned idx = (unsigned)(i * 64 + l);
        const unsigned row = idx / 21u;
        const unsigned w   = idx - row * 21u;
        const unsigned g   = (w < 7u) ? (w + 27u) : (w + 29u);
        const float* src = gbase + (size_t)row * 216u + (size_t)g * 4u;
        __builtin_amdgcn_global_load_lds((gptr_t)src, (lptr_t)(&bufB[i * 64]),
                                         16, 0, 0);
    }

    float qx[NJ], qy[NJ], qz[NJ];
    qx[0] = 0.0f; qy[0] = 0.0f; qz[0] = 0.0f;

#define LOADM(rb, o) { \
    const float4 w0 = (rb)[(o)/4 + 0]; \
    const float4 w1 = (rb)[(o)/4 + 1]; \
    const float4 w2 = (rb)[(o)/4 + 2]; \
    const float tt[12] = {w0.x,w0.y,w0.z,w0.w, w1.x,w1.y,w1.z,w1.w, \
                          w2.x,w2.y,w2.z,w2.w}; \
    r[0]=tt[(o)%4+0]; r[1]=tt[(o)%4+1]; r[2]=tt[(o)%4+2]; \
    r[3]=tt[(o)%4+3]; r[4]=tt[(o)%4+4]; r[5]=tt[(o)%4+5]; \
    r[6]=tt[(o)%4+6]; r[7]=tt[(o)%4+7]; r[8]=tt[(o)%4+8]; }

#define CHILD(p, c) { \
    const float vx = off[3*(c)+1]; \
    const float vy = off[3*(c)+2]; \
    const float vz = off[3*(c)+0]; \
    qx[c] = fmaf(r[0], vx, fmaf(r[1], vy, fmaf(r[2], vz, qx[p]))); \
    qy[c] = fmaf(r[3], vx, fmaf(r[4], vy, fmaf(r[5], vz, qy[p]))); \
    qz[c] = fmaf(r[6], vx, fmaf(r[7], vy, fmaf(r[8], vz, qz[p]))); }

    // ---- Stage A: wait only for A's 23 DMAs (B's 21 still in flight) ----
    WAITVM(21);
    {
        const float4* __restrict__ rb = &bufA[l * 23];
        float r[9];
        LOADM(rb, 0);   CHILD(0, 1);  CHILD(0, 2);  CHILD(0, 3);
        LOADM(rb, 9);   CHILD(1, 4);
        LOADM(rb, 18);  CHILD(2, 5);
        LOADM(rb, 27);  CHILD(3, 6);
        LOADM(rb, 36);  CHILD(4, 7);
        LOADM(rb, 45);  CHILD(5, 8);
        LOADM(rb, 54);  CHILD(6, 9);
        LOADM(rb, 63);  CHILD(7, 10);
        LOADM(rb, 72);  CHILD(8, 11);
        LOADM(rb, 81);  CHILD(9, 12); CHILD(9, 13); CHILD(9, 14);
    }

    // ---- Stage B: B resident (latency hidden under stage A) ----
    WAITVM(0);
    {
        const float4* __restrict__ rb = &bufB[l * 21];
        float r[9];
        LOADM(rb, 0);   CHILD(12, 15);
        LOADM(rb, 9);   CHILD(13, 16);
        LOADM(rb, 18);  CHILD(14, 17);
        LOADM(rb, 28);  CHILD(16, 18);
        LOADM(rb, 37);  CHILD(17, 19);
        LOADM(rb, 46);  CHILD(18, 20);
        LOADM(rb, 55);  CHILD(19, 21);
        LOADM(rb, 64);  CHILD(20, 22);
        LOADM(rb, 73);  CHILD(21, 23);
    }
#undef LOADM
#undef CHILD

    float fv[72];
#pragma unroll
    for (int i = 0; i < NJ; ++i) {
        fv[3*i+0] = qx[i];
        fv[3*i+1] = qy[i];
        fv[3*i+2] = qz[i];
    }

    // ---- Stage output in bufA (plain ds ops, compiler-tracked; single
    //      wave -> no barriers needed), stride 19 f4, then coalesced stores.
    float4* __restrict__ so4 = (float4*)s4;
#pragma unroll
    for (int j = 0; j < 18; ++j)
        so4[l * 19 + j] = make_float4(fv[4*j+0], fv[4*j+1], fv[4*j+2], fv[4*j+3]);

    float4* __restrict__ o4 = (float4*)(out + tile * (64LL * 72));
#pragma unroll
    for (int j = 0; j < 18; ++j) {
        const unsigned g2   = (unsigned)(j * 64 + l);
        const unsigned row2 = g2 / 18u;
        const unsigned w2   = g2 - row2 * 18u;
        o4[g2] = so4[row2 * 19u + w2];
    }
}

extern "C" void kernel_launch(void* const* d_in, const int* in_sizes, int n_in,
                              void* d_out, int out_size, void* d_ws, size_t ws_size,
                              hipStream_t stream) {
    const float* ori = (const float*)d_in[0];   // [B,24,3,3] fp32
    const float* off = (const float*)d_in[1];   // [24,3] fp32
    float* out = (float*)d_out;                 // [B,24,3] fp32

    int B  = in_sizes[0] / 216;                 // 524288
    int nt = B / 64;                            // 8192 tiles
    hipLaunchKernelGGL(fk_kernel, dim3(nt), dim3(64), 0, stream,
                       ori, off, out, nt);
}